// Round 1
// baseline (490.780 us; speedup 1.0000x reference)
//
#include <hip/hip_runtime.h>

#define N_ROWS 16384
#define DIM    4096
#define NE     64
#define NC     128   // 2*NE (gate cols | noise cols)
#define TOPK   8
#define BM     32
#define BK     64
#define NKT    (DIM / BK)

typedef _Float16 f16;
typedef _Float16 f16x4 __attribute__((ext_vector_type(4)));
typedef _Float16 f16x8 __attribute__((ext_vector_type(8)));
typedef float    f32x4 __attribute__((ext_vector_type(4)));

#define LO_SCALE     2048.0f
#define INV_LO_SCALE (1.0f / 2048.0f)

// ---- prep: W[4096][64] x2  ->  WT[128][4096] fp16 hi/lo (lo pre-scaled by 2^11) ----
__global__ __launch_bounds__(256) void prep_wt(const float* __restrict__ Wg,
                                               const float* __restrict__ Wn,
                                               f16* __restrict__ WThi,
                                               f16* __restrict__ WTlo) {
    int gid = blockIdx.x * 256 + threadIdx.x;      // NC*DIM total
    int c = gid >> 12;                             // / DIM
    int k = gid & (DIM - 1);
    float v = (c < NE) ? Wg[(size_t)k * NE + c] : Wn[(size_t)k * NE + (c - NE)];
    f16 hi = (f16)v;
    f16 lo = (f16)((v - (float)hi) * LO_SCALE);
    WThi[gid] = hi;   // [c][k], k contiguous -> coalesced writes
    WTlo[gid] = lo;
}

// ---- main fused kernel ----
__global__ __launch_bounds__(256, 2) void router_main(
    const float* __restrict__ x,
    const float* __restrict__ bg,
    const float* __restrict__ bn,
    const float* __restrict__ eps,
    const f16* __restrict__ WThi,
    const f16* __restrict__ WTlo,
    float* __restrict__ gates,
    float* __restrict__ logits)
{
    __shared__ f16   Ah[BM][BK];          // XOR-swizzled: half-idx ^= (row&7)<<3
    __shared__ f16   Al[BM][BK];
    __shared__ float Lrow[2][BM][NC + 1]; // per-ksplit partial pre-logits, +1 pad

    const int tid  = threadIdx.x;
    const int lane = tid & 63;
    const int wid  = tid >> 6;       // 0..3
    const int chalf  = wid & 1;      // which 64-col half (gate vs noise)
    const int ksplit = wid >> 1;     // which 32-k half of each BK tile
    const int row0 = blockIdx.x * BM;

    // staging map: two float4 per thread covering [32][64] fp32
    const int r0  = tid >> 4;               // 0..15
    const int kc  = (tid & 15) << 2;        // 0..60
    const int ksw0 = kc ^ ((r0 & 7) << 3);
    const int r1  = r0 + 16;
    const int ksw1 = kc ^ ((r1 & 7) << 3);

    const int l15  = lane & 15;
    const int karow = ksplit * 32 + ((lane >> 4) << 3);   // k half-index (mult of 8)

    // B: [col][k] fp16, col = chalf*64 + s*16 + l15
    const f16* bh0 = WThi + (size_t)(chalf * NE + l15) * DIM + karow;
    const f16* bl0 = WTlo + (size_t)(chalf * NE + l15) * DIM + karow;

    f32x4 acch[2][4], accl[2][4];
    #pragma unroll
    for (int b = 0; b < 2; ++b)
        #pragma unroll
        for (int s = 0; s < 4; ++s) {
            acch[b][s] = (f32x4){0.f, 0.f, 0.f, 0.f};
            accl[b][s] = (f32x4){0.f, 0.f, 0.f, 0.f};
        }

    const float* xp0 = x + (size_t)(row0 + r0) * DIM + kc;
    const float* xp1 = x + (size_t)(row0 + r1) * DIM + kc;

    for (int kt = 0; kt < NKT; ++kt) {
        // issue next A-tile loads before the barrier (overlap w/ prev compute)
        const float4 v0 = *(const float4*)(xp0 + kt * BK);
        const float4 v1 = *(const float4*)(xp1 + kt * BK);
        __syncthreads();   // everyone done reading previous tile
        {
            f16 h0=(f16)v0.x, h1=(f16)v0.y, h2=(f16)v0.z, h3=(f16)v0.w;
            *(f16x4*)&Ah[r0][ksw0] = (f16x4){h0, h1, h2, h3};
            *(f16x4*)&Al[r0][ksw0] = (f16x4){
                (f16)((v0.x - (float)h0) * LO_SCALE), (f16)((v0.y - (float)h1) * LO_SCALE),
                (f16)((v0.z - (float)h2) * LO_SCALE), (f16)((v0.w - (float)h3) * LO_SCALE)};
            f16 g0=(f16)v1.x, g1=(f16)v1.y, g2=(f16)v1.z, g3=(f16)v1.w;
            *(f16x4*)&Ah[r1][ksw1] = (f16x4){g0, g1, g2, g3};
            *(f16x4*)&Al[r1][ksw1] = (f16x4){
                (f16)((v1.x - (float)g0) * LO_SCALE), (f16)((v1.y - (float)g1) * LO_SCALE),
                (f16)((v1.z - (float)g2) * LO_SCALE), (f16)((v1.w - (float)g3) * LO_SCALE)};
        }
        __syncthreads();

        f16x8 bh[4], bl[4];
        #pragma unroll
        for (int s = 0; s < 4; ++s) {
            bh[s] = *(const f16x8*)(bh0 + (size_t)s * 16 * DIM + kt * BK);
            bl[s] = *(const f16x8*)(bl0 + (size_t)s * 16 * DIM + kt * BK);
        }
        #pragma unroll
        for (int b = 0; b < 2; ++b) {
            const int arow = b * 16 + l15;
            const int ka = karow ^ ((arow & 7) << 3);
            const f16x8 ahi = *(const f16x8*)&Ah[arow][ka];
            const f16x8 alo = *(const f16x8*)&Al[arow][ka];
            #pragma unroll
            for (int s = 0; s < 4; ++s) {
                acch[b][s] = __builtin_amdgcn_mfma_f32_16x16x32_f16(ahi, bh[s], acch[b][s], 0, 0, 0);
                accl[b][s] = __builtin_amdgcn_mfma_f32_16x16x32_f16(ahi, bl[s], accl[b][s], 0, 0, 0);
                accl[b][s] = __builtin_amdgcn_mfma_f32_16x16x32_f16(alo, bh[s], accl[b][s], 0, 0, 0);
            }
        }
    }

    // C/D layout (m89-verified): col = lane&15, row = (lane>>4)*4 + j
    #pragma unroll
    for (int b = 0; b < 2; ++b) {
        const int rr = b * 16 + ((lane >> 4) << 2);
        #pragma unroll
        for (int s = 0; s < 4; ++s) {
            const int cc = chalf * NE + s * 16 + l15;
            #pragma unroll
            for (int j = 0; j < 4; ++j)
                Lrow[ksplit][rr + j][cc] = acch[b][s][j] + accl[b][s][j] * INV_LO_SCALE;
        }
    }
    __syncthreads();

    // ---- epilogue: 8 rows per wave, lane = expert ----
    const float bgv = bg[lane];
    const float bnv = bn[lane];

    #pragma unroll 1
    for (int it = 0; it < 8; ++it) {
        const int r    = wid * 8 + it;
        const int grow = row0 + r;
        const float gl = Lrow[0][r][lane]      + Lrow[1][r][lane];
        const float nl = Lrow[0][r][NE + lane] + Lrow[1][r][NE + lane];
        const float ev = eps[(size_t)grow * NE + lane];
        const float z  = nl + bnv;
        const float sp = fmaxf(z, 0.0f) + log1pf(expf(-fabsf(z)));   // softplus
        const float lg = gl + bgv + ev * (sp + 0.01f);

        Lrow[0][r][lane] = lg;       // own column: no cross-lane hazard on gl read
        __syncthreads();             // publish lg for rank pass (uniform)

        int cnt = 0;
        #pragma unroll 8
        for (int e = 0; e < NE; ++e) {
            const float v = Lrow[0][r][e];                 // broadcast read
            cnt += (v > lg) | ((v == lg) & (e < lane));    // lax.top_k tie-break: lower idx first
        }

        float m = lg;
        #pragma unroll
        for (int off = 32; off; off >>= 1) m = fmaxf(m, __shfl_xor(m, off, 64));
        const float p = (cnt < TOPK) ? expf(lg - m) : 0.0f;
        float sum = p;
        #pragma unroll
        for (int off = 32; off; off >>= 1) sum += __shfl_xor(sum, off, 64);

        gates [(size_t)grow * NE + lane] = p / sum;
        logits[(size_t)grow * NE + lane] = lg;
        __syncthreads();             // row buffer reuse safety across iterations
    }
}

extern "C" void kernel_launch(void* const* d_in, const int* in_sizes, int n_in,
                              void* d_out, int out_size, void* d_ws, size_t ws_size,
                              hipStream_t stream) {
    const float* x   = (const float*)d_in[0];
    const float* Wg  = (const float*)d_in[1];
    const float* bg  = (const float*)d_in[2];
    const float* Wn  = (const float*)d_in[3];
    const float* bn  = (const float*)d_in[4];
    const float* eps = (const float*)d_in[5];

    float* gates  = (float*)d_out;
    float* logits = (float*)d_out + (size_t)N_ROWS * NE;

    f16* WThi = (f16*)d_ws;
    f16* WTlo = WThi + (size_t)NC * DIM;   // +1 MB

    prep_wt<<<(NC * DIM) / 256, 256, 0, stream>>>(Wg, Wn, WThi, WTlo);
    router_main<<<N_ROWS / BM, 256, 0, stream>>>(x, bg, bn, eps, WThi, WTlo, gates, logits);
}

// Round 2
// 452.922 us; speedup vs baseline: 1.0836x; 1.0836x over previous
//
#include <hip/hip_runtime.h>

#define N_ROWS 16384
#define DIM    4096
#define NE     64
#define NC     128   // gate cols | noise cols
#define TOPK   8
#define BM     32
#define BK     128
#define NKT    (DIM / BK)   // 32

typedef _Float16 f16;
typedef _Float16 f16x4 __attribute__((ext_vector_type(4)));
typedef _Float16 f16x8 __attribute__((ext_vector_type(8)));
typedef float    f32x4 __attribute__((ext_vector_type(4)));

#define LO_SCALE     2048.0f
#define INV_LO_SCALE (1.0f / 2048.0f)

// ---- prep: W[4096][64] x2 -> WT[128][4096] fp16 hi/lo (lo pre-scaled 2^11) ----
__global__ __launch_bounds__(256) void prep_wt(const float* __restrict__ Wg,
                                               const float* __restrict__ Wn,
                                               f16* __restrict__ WThi,
                                               f16* __restrict__ WTlo) {
    int gid = blockIdx.x * 256 + threadIdx.x;      // NC*DIM total
    int c = gid >> 12;                             // / DIM
    int k = gid & (DIM - 1);
    float v = (c < NE) ? Wg[(size_t)k * NE + c] : Wn[(size_t)k * NE + (c - NE)];
    f16 hi = (f16)v;
    f16 lo = (f16)((v - (float)hi) * LO_SCALE);
    WThi[gid] = hi;
    WTlo[gid] = lo;
}

// ---- main fused kernel ----
__global__ __launch_bounds__(256, 2) void router_main(
    const float* __restrict__ x,
    const float* __restrict__ bg,
    const float* __restrict__ bn,
    const float* __restrict__ eps,
    const f16* __restrict__ WThi,
    const f16* __restrict__ WTlo,
    float* __restrict__ gates,
    float* __restrict__ logits)
{
    // double-buffered A tiles, XOR-swizzled at 8-elem octet granularity:
    // elem(r,k) lives at r*BK + ((k>>3)^(r&7))*8 + (k&7)  -> 2-way-max read conflict
    __shared__ f16   Ah[2][BM * BK];
    __shared__ f16   Al[2][BM * BK];
    __shared__ float Lrow[BM][NC + 2];

    const int tid  = threadIdx.x;
    const int lane = tid & 63;
    const int wid  = tid >> 6;        // 0..3: wave owns 32 output cols, full K
    const int l15  = lane & 15;
    const int lk   = lane >> 4;       // 0..3
    const int row0 = blockIdx.x * BM;

    // staging geometry: thread covers rows sr+{0,8,16,24}, f32 col group c4 (4 cols)
    const int sr = tid >> 5;          // 0..7
    const int c4 = tid & 31;          // 0..31
    const int o  = c4 >> 1;           // 32B octet within row
    const int h  = c4 & 1;
    const float* xbase = x + (size_t)(row0 + sr) * DIM + c4 * 4;

    // B pointers: col = wid*32 + s*16 + l15 ; k-lane base = lk*8
    const f16* bhp = WThi + (size_t)(wid * 32 + l15) * DIM + lk * 8;
    const f16* blp = WTlo + (size_t)(wid * 32 + l15) * DIM + lk * 8;

    f32x4 acch[2][2], accl[2][2];
    #pragma unroll
    for (int b = 0; b < 2; ++b)
        #pragma unroll
        for (int s = 0; s < 2; ++s) {
            acch[b][s] = (f32x4){0.f, 0.f, 0.f, 0.f};
            accl[b][s] = (f32x4){0.f, 0.f, 0.f, 0.f};
        }

    float4 v[4];

#define LOADX(kt_)                                                              \
    _Pragma("unroll")                                                           \
    for (int i = 0; i < 4; ++i)                                                 \
        v[i] = *(const float4*)(xbase + (size_t)(kt_) * BK + (size_t)i * 8 * DIM);

#define STAGE(pp)                                                               \
    _Pragma("unroll")                                                           \
    for (int i = 0; i < 4; ++i) {                                               \
        const int rr = sr + 8 * i;                                              \
        const int e  = rr * BK + ((o ^ (rr & 7)) << 3) + h * 4;                 \
        f16 a0 = (f16)v[i].x, a1 = (f16)v[i].y, a2 = (f16)v[i].z, a3 = (f16)v[i].w; \
        *(f16x4*)&Ah[pp][e] = (f16x4){a0, a1, a2, a3};                          \
        *(f16x4*)&Al[pp][e] = (f16x4){                                          \
            (f16)((v[i].x - (float)a0) * LO_SCALE),                             \
            (f16)((v[i].y - (float)a1) * LO_SCALE),                             \
            (f16)((v[i].z - (float)a2) * LO_SCALE),                             \
            (f16)((v[i].w - (float)a3) * LO_SCALE)};                            \
    }

    // prologue: stage tile 0, prefetch tile 1
    LOADX(0);
    STAGE(0);
    LOADX(1);
    __syncthreads();

    for (int kt = 0; kt < NKT; ++kt) {
        const int p = kt & 1;
        if (kt + 1 < NKT) STAGE(p ^ 1);

        // B fragments for this K-tile (16 x 16B, L1/L2-hot)
        f16x8 bh[4][2], bl[4][2];
        #pragma unroll
        for (int ks = 0; ks < 4; ++ks)
            #pragma unroll
            for (int s = 0; s < 2; ++s) {
                bh[ks][s] = *(const f16x8*)(bhp + (size_t)s * 16 * DIM + kt * BK + ks * 32);
                bl[ks][s] = *(const f16x8*)(blp + (size_t)s * 16 * DIM + kt * BK + ks * 32);
            }

        // issue next x prefetch AFTER the B loads (younger: counted vmcnt for B
        // won't drain it; it stays in flight until next iteration's STAGE)
        if (kt + 2 < NKT) LOADX(kt + 2);

        #pragma unroll
        for (int ks = 0; ks < 4; ++ks) {
            f16x8 ah[2], al[2];
            #pragma unroll
            for (int b = 0; b < 2; ++b) {
                const int ar = b * 16 + l15;
                const int e  = ar * BK + (((ks * 4 + lk) ^ (ar & 7)) << 3);
                ah[b] = *(const f16x8*)&Ah[p][e];
                al[b] = *(const f16x8*)&Al[p][e];
            }
            #pragma unroll
            for (int b = 0; b < 2; ++b)
                #pragma unroll
                for (int s = 0; s < 2; ++s) {
                    acch[b][s] = __builtin_amdgcn_mfma_f32_16x16x32_f16(ah[b], bh[ks][s], acch[b][s], 0, 0, 0);
                    accl[b][s] = __builtin_amdgcn_mfma_f32_16x16x32_f16(ah[b], bl[ks][s], accl[b][s], 0, 0, 0);
                    accl[b][s] = __builtin_amdgcn_mfma_f32_16x16x32_f16(al[b], bh[ks][s], accl[b][s], 0, 0, 0);
                }
        }
        __syncthreads();
    }

    // C/D layout (m89-verified): col = lane&15, row = (lane>>4)*4 + j
    #pragma unroll
    for (int b = 0; b < 2; ++b) {
        const int rr = b * 16 + (lk << 2);
        #pragma unroll
        for (int s = 0; s < 2; ++s) {
            const int cc = wid * 32 + s * 16 + l15;
            #pragma unroll
            for (int j = 0; j < 4; ++j)
                Lrow[rr + j][cc] = acch[b][s][j] + accl[b][s][j] * INV_LO_SCALE;
        }
    }
    __syncthreads();   // Lrow complete (rows need cols from all waves)

    // ---- epilogue: wave wid owns rows wid*8 .. wid*8+7, lane = expert ----
    const float bgv = bg[lane];
    const float bnv = bn[lane];
    float lgv[8];

    #pragma unroll
    for (int it = 0; it < 8; ++it) {
        const int r    = wid * 8 + it;
        const int grow = row0 + r;
        const float gl = Lrow[r][lane];
        const float nl = Lrow[r][NE + lane];
        const float ev = eps[(size_t)grow * NE + lane];
        const float z  = nl + bnv;
        const float sp = fmaxf(z, 0.0f) + log1pf(expf(-fabsf(z)));   // softplus
        const float lg = gl + bgv + ev * (sp + 0.01f);
        lgv[it] = lg;
        Lrow[r][lane] = lg;          // own column; consumed after barrier
    }
    __syncthreads();                 // publish lg (also orders intra-wave LDS)

    #pragma unroll 1
    for (int it = 0; it < 8; ++it) {
        const int r    = wid * 8 + it;
        const int grow = row0 + r;
        const float lg = lgv[it];

        int cnt = 0;
        #pragma unroll 8
        for (int e = 0; e < NE; ++e) {
            const float q = Lrow[r][e];                    // broadcast read
            cnt += (q > lg) | ((q == lg) & (e < lane));    // lax.top_k tie-break
        }

        float m = lg;
        #pragma unroll
        for (int off = 32; off; off >>= 1) m = fmaxf(m, __shfl_xor(m, off, 64));
        const float pv = (cnt < TOPK) ? expf(lg - m) : 0.0f;
        float sum = pv;
        #pragma unroll
        for (int off = 32; off; off >>= 1) sum += __shfl_xor(sum, off, 64);

        gates [(size_t)grow * NE + lane] = pv / sum;
        logits[(size_t)grow * NE + lane] = lg;
    }
}

extern "C" void kernel_launch(void* const* d_in, const int* in_sizes, int n_in,
                              void* d_out, int out_size, void* d_ws, size_t ws_size,
                              hipStream_t stream) {
    const float* x   = (const float*)d_in[0];
    const float* Wg  = (const float*)d_in[1];
    const float* bg  = (const float*)d_in[2];
    const float* Wn  = (const float*)d_in[3];
    const float* bn  = (const float*)d_in[4];
    const float* eps = (const float*)d_in[5];

    float* gates  = (float*)d_out;
    float* logits = (float*)d_out + (size_t)N_ROWS * NE;

    f16* WThi = (f16*)d_ws;
    f16* WTlo = WThi + (size_t)NC * DIM;

    prep_wt<<<(NC * DIM) / 256, 256, 0, stream>>>(Wg, Wn, WThi, WTlo);
    router_main<<<N_ROWS / BM, 256, 0, stream>>>(x, bg, bn, eps, WThi, WTlo, gates, logits);
}